// Round 8
// baseline (321.763 us; speedup 1.0000x reference)
//
#include <hip/hip_runtime.h>
#include <hip/hip_bf16.h>
#include <math.h>

#define N_PTS 8192
#define C_IN  256
#define OUT_C 256
#define NSAMP 16
#define H_W   32
#define EPSBN 1e-5f
#define GDIM  8
#define NCELL (GDIM * GDIM * GDIM)
#define CAPC  768
#define CAP_H 56

typedef short bf16x8 __attribute__((ext_vector_type(8)));
typedef float f32x4  __attribute__((ext_vector_type(4)));

// EXACT arithmetic from the passing rounds: plain expression, default
// compiler contraction, shared by all scans. Do NOT change the rounding.
__device__ __forceinline__ float dist2(const float4 a, const float4 b) {
  float dot = a.x * b.x + a.y * b.y + a.z * b.z;
  return a.w + b.w - 2.0f * dot;
}

__device__ __forceinline__ unsigned long long make_key(float d, int j) {
  unsigned int di = __float_as_uint(d);
  unsigned int ord = ((int)di >= 0) ? (di ^ 0x80000000u) : ~di;
  return ((unsigned long long)ord << 32) | (unsigned int)j;
}

// ak sorted DESCENDING: ak[0] = largest kept (16th-smallest overall)
__device__ __forceinline__ void chain_insert(unsigned long long (&ak)[16], unsigned long long key) {
  if (key < ak[0]) {
    #pragma unroll
    for (int s = 0; s < 15; ++s) {
      unsigned long long mn = ak[s] < key ? ak[s] : key;
      unsigned long long nx = ak[s + 1];
      ak[s] = nx > mn ? nx : mn;
    }
    ak[15] = ak[15] < key ? ak[15] : key;
  }
}

// ---------------------------------------------------------------- prep
__global__ __launch_bounds__(256) void prep_kernel(
    const float* __restrict__ p,
    const float* __restrict__ wq, const float* __restrict__ wk, const float* __restrict__ wv,
    const float* __restrict__ bq, const float* __restrict__ bk, const float* __restrict__ bv,
    const float* __restrict__ l1w, const float* __restrict__ l2w,
    float4* __restrict__ p4, __hip_bfloat16* __restrict__ Bp, float* __restrict__ biasp,
    __hip_bfloat16* __restrict__ l1wp, __hip_bfloat16* __restrict__ l2wp,
    int* __restrict__ hist, int* __restrict__ pt_cell) {
  int tid = blockIdx.x * blockDim.x + threadIdx.x;
  if (tid < 48 * 32 * 16 * 8) {
    int kj = tid & 7, n = (tid >> 3) & 15, kb = (tid >> 7) & 31, nt = tid >> 12;
    int k = kb * 8 + kj, col = nt * 16 + n;
    float v;
    if (col < 256)      v = wq[k * 256 + col];
    else if (col < 512) v = wk[k * 256 + (col - 256)];
    else                v = wv[k * 256 + (col - 512)];
    Bp[tid] = __float2bfloat16(v);
  }
  if (tid < 768) {
    biasp[tid] = tid < 256 ? bq[tid] : (tid < 512 ? bk[tid - 256] : bv[tid - 512]);
  }
  if (tid < 8192) {
    int kj = tid & 7, n = (tid >> 3) & 15, kb = (tid >> 7) & 31, nt = (tid >> 12) & 1;
    int k = kb * 8 + kj, col = nt * 16 + n;
    l1wp[tid] = __float2bfloat16(l1w[k * 32 + col]);
  }
  if (tid < 1024) {
    int kj = tid & 7, n = (tid >> 3) & 15, kb = (tid >> 7) & 3, nt = (tid >> 9) & 1;
    int k = kb * 8 + kj, col = nt * 16 + n;
    l2wp[tid] = __float2bfloat16(l2w[k * 32 + col]);
  }
  if (tid < N_PTS) {
    float px = p[tid * 3 + 0], py = p[tid * 3 + 1], pz = p[tid * 3 + 2];
    float sq = px * px;
    sq += py * py;
    sq += pz * pz;
    p4[tid] = make_float4(px, py, pz, sq);
    int cx = min(GDIM - 1, max(0, (int)(px * GDIM)));
    int cy = min(GDIM - 1, max(0, (int)(py * GDIM)));
    int cz = min(GDIM - 1, max(0, (int)(pz * GDIM)));
    int cell = (cz * GDIM + cy) * GDIM + cx;
    pt_cell[tid] = cell;
    atomicAdd(&hist[cell], 1);
  }
}

// ---------------------------------------------------------------- grid scan
__global__ __launch_bounds__(512) void scan512(const int* __restrict__ hist, int* __restrict__ cell_start) {
  __shared__ int buf[NCELL];
  int t = threadIdx.x;
  buf[t] = hist[t];
  __syncthreads();
  for (int off = 1; off < NCELL; off <<= 1) {
    int add = (t >= off) ? buf[t - off] : 0;
    __syncthreads();
    buf[t] += add;
    __syncthreads();
  }
  cell_start[t + 1] = buf[t];
  if (t == 0) cell_start[0] = 0;
}

// ---------------------------------------------------------------- scatter (also emits orig->sorted rank)
__global__ __launch_bounds__(256) void scatter_kernel(
    const float4* __restrict__ p4, const int* __restrict__ pt_cell,
    const int* __restrict__ cell_start, int* __restrict__ cursor,
    float4* __restrict__ sp4, int* __restrict__ sidx, int* __restrict__ rank) {
  int tid = blockIdx.x * blockDim.x + threadIdx.x;
  if (tid < N_PTS) {
    int c = pt_cell[tid];
    int pos = cell_start[c] + atomicAdd(&cursor[c], 1);
    sp4[pos] = p4[tid];
    sidx[pos] = tid;
    rank[tid] = pos;
  }
}

// ---------------------------------------------------------------- x -> bf16, rows in sorted order
__global__ __launch_bounds__(256) void xbf_kernel(
    const float* __restrict__ x, const int* __restrict__ sidx,
    __hip_bfloat16* __restrict__ x_bf) {
  const int b = blockIdx.x;
  const int c = threadIdx.x;
  x_bf[(size_t)b * C_IN + c] = __float2bfloat16(x[(size_t)sidx[b] * C_IN + c]);
}

// ---------------------------------------------------------------- exact grid KNN: radius collect + rank select
__global__ __launch_bounds__(256) void knn_grid(
    const float4* __restrict__ sp4, const int* __restrict__ sidx,
    const int* __restrict__ cell_start, int* __restrict__ nbr) {
  __shared__ float4 cpos[CAPC];
  __shared__ int    cidx[CAPC];
  __shared__ unsigned long long hk_s[16][CAP_H];
  __shared__ unsigned long long okey_s[16][16];
  __shared__ int cnt_s[16];
  __shared__ int cell_s0_s[27];
  __shared__ int pref_s[28];
  __shared__ int nc_s, total_s;
  __shared__ float r2_s;

  const int cell = blockIdx.x;
  const int tid = threadIdx.x;
  const int hcx = cell & 7, hcy = (cell >> 3) & 7, hcz = cell >> 6;
  const int cs = cell_start[cell], ce = cell_start[cell + 1];

  const int ax0 = max(hcx - 1, 0), ax1 = min(hcx + 1, GDIM - 1);
  const int ay0 = max(hcy - 1, 0), ay1 = min(hcy + 1, GDIM - 1);
  const int az0 = max(hcz - 1, 0), az1 = min(hcz + 1, GDIM - 1);

  if (tid == 0) {
    int off = 0, m = 0;
    for (int cz = az0; cz <= az1; ++cz)
      for (int cy = ay0; cy <= ay1; ++cy)
        for (int cx = ax0; cx <= ax1; ++cx) {
          int cc = (cz * GDIM + cy) * GDIM + cx;
          cell_s0_s[m] = cell_start[cc];
          pref_s[m] = off;
          off += cell_start[cc + 1] - cell_start[cc];
          ++m;
        }
    pref_s[m] = off;
    nc_s = m;
    total_s = off;
    // density-based collect radius: r = 1.3 * r16, r16^3 = 16 / ((4/3)*pi*rho)
    int nbc = (ax1 - ax0 + 1) * (ay1 - ay0 + 1) * (az1 - az0 + 1);
    float vol = (float)nbc / 512.0f;
    float rho = (float)off / vol;
    float r = 1.30f * cbrtf(3.8197186f / rho);
    r2_s = r * r;
  }
  __syncthreads();
  const int nc = nc_s, total = total_s;
  const float r2 = r2_s;

  for (int idx = tid; idx < total && idx < CAPC; idx += 256) {
    int c = 0;
    while (c + 1 < nc && pref_s[c + 1] <= idx) ++c;
    int g = cell_s0_s[c] + (idx - pref_s[c]);
    cpos[idx] = sp4[g];
    cidx[idx] = sidx[g];
  }
  __syncthreads();

  // thread = ptl*16 + slice
  const int ptl = tid >> 4, slice = tid & 15;

  for (int p0 = cs; p0 < ce; p0 += 16) {
    const int np = min(16, ce - p0);
    const bool pok = ptl < np;
    const int ld = pok ? (p0 + ptl) : cs;
    const float4 pi = sp4[ld];
    const int orig = sidx[ld];

    if (tid < 16) cnt_s[tid] = 0;
    __syncthreads();

    // collect: cheap radius filter, u64 keys appended via LDS atomic
    if (pok) {
      for (int idx = slice; idx < total; idx += 16) {
        float4 q;
        int qi;
        if (idx < CAPC) { q = cpos[idx]; qi = cidx[idx]; }
        else {  // overflow exactness guard (~never taken)
          int c = 0;
          while (c + 1 < nc && pref_s[c + 1] <= idx) ++c;
          int g = cell_s0_s[c] + (idx - pref_s[c]);
          q = sp4[g]; qi = sidx[g];
        }
        float d = dist2(pi, q);
        if (d <= r2) {
          int pos = atomicAdd(&cnt_s[ptl], 1);
          if (pos < CAP_H) hk_s[ptl][pos] = make_key(d, qi);
        }
      }
    }
    __syncthreads();

    const int cnt = cnt_s[ptl];
    const bool fb = (cnt < 16) || (cnt > CAP_H);   // fallback (rare)

    // exact rank-select of top-16 among collected keys (independent compares)
    if (pok && !fb) {
      for (int i = slice; i < cnt; i += 16) {
        unsigned long long key = hk_s[ptl][i];
        int rk = 0;
        for (int j = 0; j < cnt; ++j) rk += (hk_s[ptl][j] < key) ? 1 : 0;
        if (rk < 16) okey_s[ptl][rk] = key;
      }
    }
    __syncthreads();

    if (slice == 0 && pok) {
      unsigned long long akm[16];
      if (!fb) {
        #pragma unroll
        for (int s = 0; s < 16; ++s) akm[s] = okey_s[ptl][15 - s];  // descending
      } else {
        #pragma unroll
        for (int s = 0; s < 16; ++s) akm[s] = ~0ULL;
        for (int idx = 0; idx < total; ++idx) {
          float4 q;
          int qi;
          if (idx < CAPC) { q = cpos[idx]; qi = cidx[idx]; }
          else {
            int c = 0;
            while (c + 1 < nc && pref_s[c + 1] <= idx) ++c;
            int g = cell_s0_s[c] + (idx - pref_s[c]);
            q = sp4[g]; qi = sidx[g];
          }
          chain_insert(akm, make_key(dist2(pi, q), qi));
        }
      }
      // phase B: ball-vs-clamped-box exactness guard
      float r;
      if (akm[0] == ~0ULL) {
        r = 1e9f;
      } else {
        unsigned int ord = (unsigned int)(akm[0] >> 32);
        unsigned int di = (ord & 0x80000000u) ? (ord ^ 0x80000000u) : ~ord;
        float d16 = __uint_as_float(di);
        r = sqrtf(fmaxf(d16, 0.f)) * 1.001f + 1e-4f;
      }
      int lx = (int)fminf(fmaxf(floorf((pi.x - r) * GDIM), 0.f), (float)(GDIM - 1));
      int ux = (int)fminf(fmaxf(floorf((pi.x + r) * GDIM), 0.f), (float)(GDIM - 1));
      int ly = (int)fminf(fmaxf(floorf((pi.y - r) * GDIM), 0.f), (float)(GDIM - 1));
      int uy = (int)fminf(fmaxf(floorf((pi.y + r) * GDIM), 0.f), (float)(GDIM - 1));
      int lz = (int)fminf(fmaxf(floorf((pi.z - r) * GDIM), 0.f), (float)(GDIM - 1));
      int uz = (int)fminf(fmaxf(floorf((pi.z + r) * GDIM), 0.f), (float)(GDIM - 1));
      if (lx < ax0 || ux > ax1 || ly < ay0 || uy > ay1 || lz < az0 || uz > az1) {
        for (int cz = lz; cz <= uz; ++cz)
          for (int cy = ly; cy <= uy; ++cy)
            for (int cx = lx; cx <= ux; ++cx) {
              if (cx >= ax0 && cx <= ax1 && cy >= ay0 && cy <= ay1 && cz >= az0 && cz <= az1)
                continue;
              int cc = (cz * GDIM + cy) * GDIM + cx;
              int s0 = cell_start[cc], e0 = cell_start[cc + 1];
              for (int k = s0; k < e0; ++k) {
                float4 q = sp4[k];
                chain_insert(akm, make_key(dist2(pi, q), sidx[k]));
              }
            }
      }
      #pragma unroll
      for (int s = 0; s < 16; ++s) nbr[orig * NSAMP + s] = (int)(akm[s] & 0xFFFFFFFFu);
    }
    __syncthreads();
  }
}

// ---------------------------------------------------------------- qkv gemm: bf16 MFMA, sorted rows, linear stores
__global__ __launch_bounds__(256) void gemm_qkv_mfma(
    const __hip_bfloat16* __restrict__ x_bf, const __hip_bfloat16* __restrict__ Bp,
    const float* __restrict__ biasp, __hip_bfloat16* __restrict__ xqkv) {
  const int w = threadIdx.x >> 6;
  const int lane = threadIdx.x & 63;
  const int gw = blockIdx.x * 4 + w;
  const int m0 = (gw & 127) * 64;
  const int nt4 = (gw >> 7) * 4;
  const int n = lane & 15, q = lane >> 4;

  f32x4 acc[4][4];
  #pragma unroll
  for (int mi = 0; mi < 4; ++mi)
    #pragma unroll
    for (int ni = 0; ni < 4; ++ni) acc[mi][ni] = (f32x4){0.f, 0.f, 0.f, 0.f};

  for (int k0 = 0; k0 < 256; k0 += 32) {
    bf16x8 af[4], bfr[4];
    #pragma unroll
    for (int mi = 0; mi < 4; ++mi)
      af[mi] = *(const bf16x8*)&x_bf[(size_t)(m0 + mi * 16 + n) * 256 + k0 + q * 8];
    #pragma unroll
    for (int ni = 0; ni < 4; ++ni)
      bfr[ni] = *(const bf16x8*)&Bp[(size_t)(nt4 + ni) * 4096 + (k0 >> 3) * 128 + q * 128 + n * 8];
    #pragma unroll
    for (int mi = 0; mi < 4; ++mi)
      #pragma unroll
      for (int ni = 0; ni < 4; ++ni)
        acc[mi][ni] = __builtin_amdgcn_mfma_f32_16x16x32_bf16(af[mi], bfr[ni], acc[mi][ni], 0, 0, 0);
  }
  #pragma unroll
  for (int ni = 0; ni < 4; ++ni) {
    int col = (nt4 + ni) * 16 + n;
    float b = biasp[col];
    #pragma unroll
    for (int mi = 0; mi < 4; ++mi)
      #pragma unroll
      for (int r = 0; r < 4; ++r)
        xqkv[(size_t)(m0 + mi * 16 + q * 4 + r) * 768 + col] = __float2bfloat16(acc[mi][ni][r] + b);
  }
}

// ---------------------------------------------------------------- fused per-point transform (sorted-space gathers)
__global__ __launch_bounds__(256) void fused_pt(
    const float4* __restrict__ sp4, const int* __restrict__ sidx, const int* __restrict__ rank,
    const __hip_bfloat16* __restrict__ xqkv, const int* __restrict__ nbr,
    const float* __restrict__ pw1, const float* __restrict__ pb1,
    const float* __restrict__ pbng, const float* __restrict__ pbnb,
    const float* __restrict__ pbnm, const float* __restrict__ pbnv,
    const float* __restrict__ pw2, const float* __restrict__ pb2,
    const float* __restrict__ bn1g, const float* __restrict__ bn1b,
    const float* __restrict__ bn1m, const float* __restrict__ bn1v,
    const __hip_bfloat16* __restrict__ l1wp, const float* __restrict__ l1b,
    const float* __restrict__ bn2g, const float* __restrict__ bn2b,
    const float* __restrict__ bn2m, const float* __restrict__ bn2v,
    const __hip_bfloat16* __restrict__ l2wp, const float* __restrict__ l2b,
    float* __restrict__ out) {
  __shared__ __align__(16) __hip_bfloat16 a_s[NSAMP][264];
  __shared__ __align__(16) __hip_bfloat16 h1_s[NSAMP][40];
  __shared__ float w_s[NSAMP][33];
  __shared__ float q3_s[NSAMP][4];
  __shared__ int jn[NSAMP];

  const int b = blockIdx.x;            // sorted position
  const int i = sidx[b];               // original index
  const int tid = threadIdx.x;

  if (tid < NSAMP) {
    int j = nbr[i * NSAMP + tid];      // orig neighbor id (exact selection)
    int k = rank[j];                   // sorted row
    jn[tid] = k;
    float4 pj = sp4[k];
    float4 pc = sp4[b];
    float rx = pj.x - pc.x;
    float ry = pj.y - pc.y;
    float rz = pj.z - pc.z;
    #pragma unroll
    for (int c3 = 0; c3 < 3; ++c3) {
      float t = rx * pw1[0 * 3 + c3] + ry * pw1[1 * 3 + c3] + rz * pw1[2 * 3 + c3] + pb1[c3];
      t = (t - pbnm[c3]) * rsqrtf(pbnv[c3] + EPSBN) * pbng[c3] + pbnb[c3];
      q3_s[tid][c3] = fmaxf(t, 0.f);
    }
  }
  __syncthreads();

  const int c = tid;
  const float xq_c = __bfloat162float(xqkv[(size_t)b * 768 + c]);
  const float s1 = bn1g[c] * rsqrtf(bn1v[c] + EPSBN);
  const float o1 = bn1b[c] - bn1m[c] * s1;
  const float w2c0 = pw2[c], w2c1 = pw2[256 + c], w2c2 = pw2[512 + c];
  const float pb2c = pb2[c];
  #pragma unroll
  for (int t = 0; t < NSAMP; ++t) {
    int k = jn[t];
    float prv = q3_s[t][0] * w2c0 + q3_s[t][1] * w2c1 + q3_s[t][2] * w2c2 + pb2c;
    float xkv = __bfloat162float(xqkv[(size_t)k * 768 + 256 + c]);
    float r = xkv - xq_c + prv;
    a_s[t][c] = __float2bfloat16(fmaxf(r * s1 + o1, 0.f));
  }
  __syncthreads();

  const int wv_ = tid >> 6;
  const int lane = tid & 63;
  const int nn = lane & 15, q = lane >> 4;
  if (wv_ < 2) {
    f32x4 acc = {0.f, 0.f, 0.f, 0.f};
    #pragma unroll
    for (int k0 = 0; k0 < 256; k0 += 32) {
      bf16x8 a = *(const bf16x8*)&a_s[nn][k0 + q * 8];
      bf16x8 bb = *(const bf16x8*)&l1wp[wv_ * 4096 + (k0 >> 3) * 128 + q * 128 + nn * 8];
      acc = __builtin_amdgcn_mfma_f32_16x16x32_bf16(a, bb, acc, 0, 0, 0);
    }
    int h = wv_ * 16 + nn;
    float s2 = bn2g[h] * rsqrtf(bn2v[h] + EPSBN);
    float o2 = bn2b[h] - bn2m[h] * s2;
    float l1bh = l1b[h];
    #pragma unroll
    for (int r = 0; r < 4; ++r)
      h1_s[q * 4 + r][h] = __float2bfloat16(fmaxf((acc[r] + l1bh) * s2 + o2, 0.f));
  }
  __syncthreads();

  if (wv_ < 2) {
    bf16x8 a = *(const bf16x8*)&h1_s[nn][q * 8];
    bf16x8 bb = *(const bf16x8*)&l2wp[wv_ * 512 + q * 128 + nn * 8];
    f32x4 z = {0.f, 0.f, 0.f, 0.f};
    f32x4 d = __builtin_amdgcn_mfma_f32_16x16x32_bf16(a, bb, z, 0, 0, 0);
    int h = wv_ * 16 + nn;
    float l2bh = l2b[h];
    #pragma unroll
    for (int r = 0; r < 4; ++r) w_s[q * 4 + r][h] = d[r] + l2bh;
  }
  __syncthreads();

  if (tid < H_W) {
    int h = tid;
    float m = -1e30f;
    #pragma unroll
    for (int t = 0; t < NSAMP; ++t) m = fmaxf(m, w_s[t][h]);
    float e[NSAMP];
    float ssum = 0.f;
    #pragma unroll
    for (int t = 0; t < NSAMP; ++t) { e[t] = __expf(w_s[t][h] - m); ssum += e[t]; }
    float inv = 1.f / ssum;
    #pragma unroll
    for (int t = 0; t < NSAMP; ++t) w_s[t][h] = e[t] * inv;
  }
  __syncthreads();

  const int h = c & 31;
  float acc6 = 0.f;
  #pragma unroll
  for (int t = 0; t < NSAMP; ++t) {
    int k = jn[t];
    float xv = __bfloat162float(xqkv[(size_t)k * 768 + 512 + c]);
    float prv = q3_s[t][0] * w2c0 + q3_s[t][1] * w2c1 + q3_s[t][2] * w2c2 + pb2c;
    acc6 += (xv + prv) * w_s[t][h];
  }
  out[(size_t)i * OUT_C + c] = acc6;
}

// ---------------------------------------------------------------- launch
extern "C" void kernel_launch(void* const* d_in, const int* in_sizes, int n_in,
                              void* d_out, int out_size, void* d_ws, size_t ws_size,
                              hipStream_t stream) {
  const float* p    = (const float*)d_in[0];
  const float* x    = (const float*)d_in[1];
  const float* wq   = (const float*)d_in[2];
  const float* bq   = (const float*)d_in[3];
  const float* wk   = (const float*)d_in[4];
  const float* bk   = (const float*)d_in[5];
  const float* wv   = (const float*)d_in[6];
  const float* bv   = (const float*)d_in[7];
  const float* pw1  = (const float*)d_in[8];
  const float* pb1  = (const float*)d_in[9];
  const float* pbng = (const float*)d_in[10];
  const float* pbnb = (const float*)d_in[11];
  const float* pbnm = (const float*)d_in[12];
  const float* pbnv = (const float*)d_in[13];
  const float* pw2  = (const float*)d_in[14];
  const float* pb2  = (const float*)d_in[15];
  const float* bn1g = (const float*)d_in[16];
  const float* bn1b = (const float*)d_in[17];
  const float* bn1m = (const float*)d_in[18];
  const float* bn1v = (const float*)d_in[19];
  const float* l1w  = (const float*)d_in[20];
  const float* l1b  = (const float*)d_in[21];
  const float* bn2g = (const float*)d_in[22];
  const float* bn2b = (const float*)d_in[23];
  const float* bn2m = (const float*)d_in[24];
  const float* bn2v = (const float*)d_in[25];
  const float* l2w  = (const float*)d_in[26];
  const float* l2b  = (const float*)d_in[27];
  float* out = (float*)d_out;

  char* ws = (char*)d_ws;
  float4* p4       = (float4*)(ws + 0x000000);
  float*  biasp    = (float*)(ws + 0x040000);
  int*    hist     = (int*)(ws + 0x042000);
  int*    cursor   = (int*)(ws + 0x042800);
  int*    cell_st  = (int*)(ws + 0x043000);
  int*    pt_cell  = (int*)(ws + 0x044000);
  float4* sp4      = (float4*)(ws + 0x050000);
  int*    sidx     = (int*)(ws + 0x070000);
  __hip_bfloat16* l1wp = (__hip_bfloat16*)(ws + 0x080000);
  __hip_bfloat16* l2wp = (__hip_bfloat16*)(ws + 0x084000);
  int*    rank     = (int*)(ws + 0x088000);
  int*    nbr      = (int*)(ws + 0x090000);
  __hip_bfloat16* Bp   = (__hip_bfloat16*)(ws + 0x110000);
  __hip_bfloat16* x_bf = (__hip_bfloat16*)(ws + 0x170000);
  __hip_bfloat16* xqkv = (__hip_bfloat16*)(ws + 0x570000);

  hipMemsetAsync(ws + 0x042000, 0, 0x1000, stream);  // hist + cursor
  prep_kernel<<<dim3(768), dim3(256), 0, stream>>>(
      p, wq, wk, wv, bq, bk, bv, l1w, l2w, p4, Bp, biasp, l1wp, l2wp,
      hist, pt_cell);
  scan512<<<dim3(1), dim3(NCELL), 0, stream>>>(hist, cell_st);
  scatter_kernel<<<dim3(32), dim3(256), 0, stream>>>(p4, pt_cell, cell_st, cursor, sp4, sidx, rank);
  xbf_kernel<<<dim3(N_PTS), dim3(256), 0, stream>>>(x, sidx, x_bf);
  gemm_qkv_mfma<<<dim3(384), dim3(256), 0, stream>>>(x_bf, Bp, biasp, xqkv);
  knn_grid<<<dim3(NCELL), dim3(256), 0, stream>>>(sp4, sidx, cell_st, nbr);
  fused_pt<<<dim3(N_PTS), dim3(256), 0, stream>>>(
      sp4, sidx, rank, xqkv, nbr, pw1, pb1, pbng, pbnb, pbnm, pbnv, pw2, pb2,
      bn1g, bn1b, bn1m, bn1v, l1wp, l1b, bn2g, bn2b, bn2m, bn2v, l2wp, l2b, out);
}

// Round 9
// 213.732 us; speedup vs baseline: 1.5055x; 1.5055x over previous
//
#include <hip/hip_runtime.h>
#include <hip/hip_bf16.h>
#include <math.h>

#define N_PTS 8192
#define C_IN  256
#define OUT_C 256
#define NSAMP 16
#define H_W   32
#define EPSBN 1e-5f
#define GDIM  8
#define NCELL (GDIM * GDIM * GDIM)
#define CAPC  768
#define CAP_H 40

typedef short bf16x8 __attribute__((ext_vector_type(8)));
typedef float f32x4  __attribute__((ext_vector_type(4)));

// EXACT arithmetic from the passing rounds: plain expression, default
// compiler contraction, shared by all scans. Do NOT change the rounding.
__device__ __forceinline__ float dist2(const float4 a, const float4 b) {
  float dot = a.x * b.x + a.y * b.y + a.z * b.z;
  return a.w + b.w - 2.0f * dot;
}

__device__ __forceinline__ unsigned long long make_key(float d, int j) {
  unsigned int di = __float_as_uint(d);
  unsigned int ord = ((int)di >= 0) ? (di ^ 0x80000000u) : ~di;
  return ((unsigned long long)ord << 32) | (unsigned int)j;
}

// ak sorted DESCENDING: ak[0] = largest kept (16th-smallest overall)
__device__ __forceinline__ void chain_insert(unsigned long long (&ak)[16], unsigned long long key) {
  if (key < ak[0]) {
    #pragma unroll
    for (int s = 0; s < 15; ++s) {
      unsigned long long mn = ak[s] < key ? ak[s] : key;
      unsigned long long nx = ak[s + 1];
      ak[s] = nx > mn ? nx : mn;
    }
    ak[15] = ak[15] < key ? ak[15] : key;
  }
}

// Merge this lane's ascending 16-float list with lane^m's; both end identical.
__device__ __forceinline__ void merge16f(float (&A)[16], int m) {
  float B[16], t[16];
  #pragma unroll
  for (int s = 0; s < 16; ++s) B[s] = __shfl_xor(A[s], m, 64);
  #pragma unroll
  for (int s = 0; s < 16; ++s) t[s] = fminf(A[s], B[15 - s]);
  #pragma unroll
  for (int k = 8; k >= 1; k >>= 1) {
    #pragma unroll
    for (int s = 0; s < 16; ++s) {
      if (!(s & k)) {
        float lo = fminf(t[s], t[s | k]);
        float hi = fmaxf(t[s], t[s | k]);
        t[s] = lo; t[s | k] = hi;
      }
    }
  }
  #pragma unroll
  for (int s = 0; s < 16; ++s) A[s] = t[s];
}

// ---------------------------------------------------------------- prep
__global__ __launch_bounds__(256) void prep_kernel(
    const float* __restrict__ p,
    const float* __restrict__ wq, const float* __restrict__ wk, const float* __restrict__ wv,
    const float* __restrict__ bq, const float* __restrict__ bk, const float* __restrict__ bv,
    const float* __restrict__ l1w, const float* __restrict__ l2w,
    float4* __restrict__ p4, __hip_bfloat16* __restrict__ Bp, float* __restrict__ biasp,
    __hip_bfloat16* __restrict__ l1wp, __hip_bfloat16* __restrict__ l2wp,
    int* __restrict__ hist, int* __restrict__ pt_cell) {
  int tid = blockIdx.x * blockDim.x + threadIdx.x;
  if (tid < 48 * 32 * 16 * 8) {
    int kj = tid & 7, n = (tid >> 3) & 15, kb = (tid >> 7) & 31, nt = tid >> 12;
    int k = kb * 8 + kj, col = nt * 16 + n;
    float v;
    if (col < 256)      v = wq[k * 256 + col];
    else if (col < 512) v = wk[k * 256 + (col - 256)];
    else                v = wv[k * 256 + (col - 512)];
    Bp[tid] = __float2bfloat16(v);
  }
  if (tid < 768) {
    biasp[tid] = tid < 256 ? bq[tid] : (tid < 512 ? bk[tid - 256] : bv[tid - 512]);
  }
  if (tid < 8192) {
    int kj = tid & 7, n = (tid >> 3) & 15, kb = (tid >> 7) & 31, nt = (tid >> 12) & 1;
    int k = kb * 8 + kj, col = nt * 16 + n;
    l1wp[tid] = __float2bfloat16(l1w[k * 32 + col]);
  }
  if (tid < 1024) {
    int kj = tid & 7, n = (tid >> 3) & 15, kb = (tid >> 7) & 3, nt = (tid >> 9) & 1;
    int k = kb * 8 + kj, col = nt * 16 + n;
    l2wp[tid] = __float2bfloat16(l2w[k * 32 + col]);
  }
  if (tid < N_PTS) {
    float px = p[tid * 3 + 0], py = p[tid * 3 + 1], pz = p[tid * 3 + 2];
    float sq = px * px;
    sq += py * py;
    sq += pz * pz;
    p4[tid] = make_float4(px, py, pz, sq);
    int cx = min(GDIM - 1, max(0, (int)(px * GDIM)));
    int cy = min(GDIM - 1, max(0, (int)(py * GDIM)));
    int cz = min(GDIM - 1, max(0, (int)(pz * GDIM)));
    int cell = (cz * GDIM + cy) * GDIM + cx;
    pt_cell[tid] = cell;
    atomicAdd(&hist[cell], 1);
  }
}

// ---------------------------------------------------------------- grid scan
__global__ __launch_bounds__(512) void scan512(const int* __restrict__ hist, int* __restrict__ cell_start) {
  __shared__ int buf[NCELL];
  int t = threadIdx.x;
  buf[t] = hist[t];
  __syncthreads();
  for (int off = 1; off < NCELL; off <<= 1) {
    int add = (t >= off) ? buf[t - off] : 0;
    __syncthreads();
    buf[t] += add;
    __syncthreads();
  }
  cell_start[t + 1] = buf[t];
  if (t == 0) cell_start[0] = 0;
}

// ---------------------------------------------------------------- scatter (also emits orig->sorted rank)
__global__ __launch_bounds__(256) void scatter_kernel(
    const float4* __restrict__ p4, const int* __restrict__ pt_cell,
    const int* __restrict__ cell_start, int* __restrict__ cursor,
    float4* __restrict__ sp4, int* __restrict__ sidx, int* __restrict__ rank) {
  int tid = blockIdx.x * blockDim.x + threadIdx.x;
  if (tid < N_PTS) {
    int c = pt_cell[tid];
    int pos = cell_start[c] + atomicAdd(&cursor[c], 1);
    sp4[pos] = p4[tid];
    sidx[pos] = tid;
    rank[tid] = pos;
  }
}

// ---------------------------------------------------------------- x -> bf16, rows in sorted order
__global__ __launch_bounds__(256) void xbf_kernel(
    const float* __restrict__ x, const int* __restrict__ sidx,
    __hip_bfloat16* __restrict__ x_bf) {
  const int b = blockIdx.x;
  const int c = threadIdx.x;
  x_bf[(size_t)b * C_IN + c] = __float2bfloat16(x[(size_t)sidx[b] * C_IN + c]);
}

// ---------------------------------------------------------------- exact grid KNN v4:
// f32 value-chain -> exact d16 -> threshold collect -> u64 rank-select.
// 2 blocks per cell, 8 points x 32 slices per block.
__global__ __launch_bounds__(256) void knn_grid(
    const float4* __restrict__ sp4, const int* __restrict__ sidx,
    const int* __restrict__ cell_start, int* __restrict__ nbr) {
  __shared__ float4 cpos[CAPC];
  __shared__ int    cidx[CAPC];
  __shared__ unsigned long long hk_s[8][CAP_H];
  __shared__ unsigned long long okey_s[8][16];
  __shared__ int cnt_s[8];
  __shared__ int cell_s0_s[27];
  __shared__ int len_s[27];
  __shared__ int pref_s[28];
  __shared__ int nc_s, total_s;

  const int cell = blockIdx.x >> 1;
  const int sub  = blockIdx.x & 1;
  const int tid = threadIdx.x;
  const int hcx = cell & 7, hcy = (cell >> 3) & 7, hcz = cell >> 6;
  const int cs = cell_start[cell], ce = cell_start[cell + 1];

  const int ax0 = max(hcx - 1, 0), ax1 = min(hcx + 1, GDIM - 1);
  const int ay0 = max(hcy - 1, 0), ay1 = min(hcy + 1, GDIM - 1);
  const int az0 = max(hcz - 1, 0), az1 = min(hcz + 1, GDIM - 1);
  const int nx = ax1 - ax0 + 1, ny = ay1 - ay0 + 1, nz = az1 - az0 + 1;
  const int nbc = nx * ny * nz;

  // parallel 27-cell segment fetch + tiny serial scan
  if (tid < nbc) {
    int cx = ax0 + tid % nx;
    int cy = ay0 + (tid / nx) % ny;
    int cz = az0 + tid / (nx * ny);
    int cc = (cz * GDIM + cy) * GDIM + cx;
    int s0 = cell_start[cc];
    cell_s0_s[tid] = s0;
    len_s[tid] = cell_start[cc + 1] - s0;
  }
  __syncthreads();
  if (tid == 0) {
    int off = 0;
    for (int m = 0; m < nbc; ++m) { pref_s[m] = off; off += len_s[m]; }
    pref_s[nbc] = off;
    nc_s = nbc;
    total_s = off;
  }
  __syncthreads();
  const int nc = nc_s, total = total_s;

  for (int idx = tid; idx < total && idx < CAPC; idx += 256) {
    int c = 0;
    while (c + 1 < nc && pref_s[c + 1] <= idx) ++c;
    int g = cell_s0_s[c] + (idx - pref_s[c]);
    cpos[idx] = sp4[g];
    cidx[idx] = sidx[g];
  }
  __syncthreads();

  const int ptl = tid >> 5, slice = tid & 31;

  for (int p0 = cs + 8 * sub; p0 < ce; p0 += 16) {
    const int np = min(8, ce - p0);
    const bool pok = ptl < np;
    const int ld = pok ? (p0 + ptl) : cs;
    const float4 pi = sp4[ld];
    const int orig = sidx[ld];

    if (tid < 8) cnt_s[tid] = 0;
    if (tid < 128) okey_s[tid >> 4][tid & 15] = ~0ULL;
    __syncthreads();

    // phase 1: per-slice f32 value top-16 chain (descending, a[0]=largest kept)
    float a[16];
    #pragma unroll
    for (int s = 0; s < 16; ++s) a[s] = 3.0e38f;
    for (int idx = slice; idx < total; idx += 32) {
      float4 q;
      if (idx < CAPC) q = cpos[idx];
      else {
        int c = 0;
        while (c + 1 < nc && pref_s[c + 1] <= idx) ++c;
        q = sp4[cell_s0_s[c] + (idx - pref_s[c])];
      }
      float d = dist2(pi, q);
      if (d < a[0]) {
        #pragma unroll
        for (int s = 0; s < 15; ++s) a[s] = fmaxf(a[s + 1], fminf(a[s], d));
        a[15] = fminf(a[15], d);
      }
    }
    // merge 32 slices (registers + shfl, no barriers): exact d16
    float asc[16];
    #pragma unroll
    for (int s = 0; s < 16; ++s) asc[s] = a[15 - s];
    merge16f(asc, 1);
    merge16f(asc, 2);
    merge16f(asc, 4);
    merge16f(asc, 8);
    merge16f(asc, 16);
    const float d16 = asc[15];  // exact 16th-smallest (or 3e38 sentinel if total<16)

    // phase 2: threshold collect of (dist, idx) keys
    if (pok) {
      for (int idx = slice; idx < total; idx += 32) {
        float4 q;
        int qi;
        if (idx < CAPC) { q = cpos[idx]; qi = cidx[idx]; }
        else {
          int c = 0;
          while (c + 1 < nc && pref_s[c + 1] <= idx) ++c;
          int g = cell_s0_s[c] + (idx - pref_s[c]);
          q = sp4[g]; qi = sidx[g];
        }
        float d = dist2(pi, q);
        if (d <= d16) {
          int pos = atomicAdd(&cnt_s[ptl], 1);
          if (pos < CAP_H) hk_s[ptl][pos] = make_key(d, qi);
        }
      }
    }
    __syncthreads();

    const int cntr = cnt_s[ptl];
    const bool overflow = cntr > CAP_H;   // ~impossible (needs 25+ exact fp32 ties)
    const int cnt = overflow ? 0 : cntr;

    // exact rank-select of top-16 among collected keys
    if (pok) {
      for (int i = slice; i < cnt; i += 32) {
        unsigned long long key = hk_s[ptl][i];
        int rk = 0;
        for (int j = 0; j < cnt; ++j) rk += (hk_s[ptl][j] < key) ? 1 : 0;
        if (rk < 16) okey_s[ptl][rk] = key;
      }
    }
    __syncthreads();

    if (slice == 0 && pok) {
      unsigned long long akm[16];
      if (!overflow) {
        #pragma unroll
        for (int s = 0; s < 16; ++s) akm[s] = okey_s[ptl][15 - s];  // descending
      } else {
        #pragma unroll
        for (int s = 0; s < 16; ++s) akm[s] = ~0ULL;
        for (int idx = 0; idx < total; ++idx) {
          float4 q; int qi;
          if (idx < CAPC) { q = cpos[idx]; qi = cidx[idx]; }
          else {
            int c = 0;
            while (c + 1 < nc && pref_s[c + 1] <= idx) ++c;
            int g = cell_s0_s[c] + (idx - pref_s[c]);
            q = sp4[g]; qi = sidx[g];
          }
          chain_insert(akm, make_key(dist2(pi, q), qi));
        }
      }
      // phase B: ball-vs-clamped-box exactness guard
      float r;
      if (akm[0] == ~0ULL) {
        r = 1e9f;
      } else {
        unsigned int ord = (unsigned int)(akm[0] >> 32);
        unsigned int di = (ord & 0x80000000u) ? (ord ^ 0x80000000u) : ~ord;
        float dd = __uint_as_float(di);
        r = sqrtf(fmaxf(dd, 0.f)) * 1.001f + 1e-4f;
      }
      int lx = (int)fminf(fmaxf(floorf((pi.x - r) * GDIM), 0.f), (float)(GDIM - 1));
      int ux = (int)fminf(fmaxf(floorf((pi.x + r) * GDIM), 0.f), (float)(GDIM - 1));
      int ly = (int)fminf(fmaxf(floorf((pi.y - r) * GDIM), 0.f), (float)(GDIM - 1));
      int uy = (int)fminf(fmaxf(floorf((pi.y + r) * GDIM), 0.f), (float)(GDIM - 1));
      int lz = (int)fminf(fmaxf(floorf((pi.z - r) * GDIM), 0.f), (float)(GDIM - 1));
      int uz = (int)fminf(fmaxf(floorf((pi.z + r) * GDIM), 0.f), (float)(GDIM - 1));
      if (lx < ax0 || ux > ax1 || ly < ay0 || uy > ay1 || lz < az0 || uz > az1) {
        for (int cz = lz; cz <= uz; ++cz)
          for (int cy = ly; cy <= uy; ++cy)
            for (int cx = lx; cx <= ux; ++cx) {
              if (cx >= ax0 && cx <= ax1 && cy >= ay0 && cy <= ay1 && cz >= az0 && cz <= az1)
                continue;
              int cc = (cz * GDIM + cy) * GDIM + cx;
              int s0 = cell_start[cc], e0 = cell_start[cc + 1];
              for (int k = s0; k < e0; ++k) {
                float4 q = sp4[k];
                chain_insert(akm, make_key(dist2(pi, q), sidx[k]));
              }
            }
      }
      #pragma unroll
      for (int s = 0; s < 16; ++s) nbr[orig * NSAMP + s] = (int)(akm[s] & 0xFFFFFFFFu);
    }
    __syncthreads();
  }
}

// ---------------------------------------------------------------- qkv gemm: bf16 MFMA, sorted rows, linear stores
__global__ __launch_bounds__(256) void gemm_qkv_mfma(
    const __hip_bfloat16* __restrict__ x_bf, const __hip_bfloat16* __restrict__ Bp,
    const float* __restrict__ biasp, __hip_bfloat16* __restrict__ xqkv) {
  const int w = threadIdx.x >> 6;
  const int lane = threadIdx.x & 63;
  const int gw = blockIdx.x * 4 + w;
  const int m0 = (gw & 127) * 64;
  const int nt4 = (gw >> 7) * 4;
  const int n = lane & 15, q = lane >> 4;

  f32x4 acc[4][4];
  #pragma unroll
  for (int mi = 0; mi < 4; ++mi)
    #pragma unroll
    for (int ni = 0; ni < 4; ++ni) acc[mi][ni] = (f32x4){0.f, 0.f, 0.f, 0.f};

  for (int k0 = 0; k0 < 256; k0 += 32) {
    bf16x8 af[4], bfr[4];
    #pragma unroll
    for (int mi = 0; mi < 4; ++mi)
      af[mi] = *(const bf16x8*)&x_bf[(size_t)(m0 + mi * 16 + n) * 256 + k0 + q * 8];
    #pragma unroll
    for (int ni = 0; ni < 4; ++ni)
      bfr[ni] = *(const bf16x8*)&Bp[(size_t)(nt4 + ni) * 4096 + (k0 >> 3) * 128 + q * 128 + n * 8];
    #pragma unroll
    for (int mi = 0; mi < 4; ++mi)
      #pragma unroll
      for (int ni = 0; ni < 4; ++ni)
        acc[mi][ni] = __builtin_amdgcn_mfma_f32_16x16x32_bf16(af[mi], bfr[ni], acc[mi][ni], 0, 0, 0);
  }
  #pragma unroll
  for (int ni = 0; ni < 4; ++ni) {
    int col = (nt4 + ni) * 16 + n;
    float b = biasp[col];
    #pragma unroll
    for (int mi = 0; mi < 4; ++mi)
      #pragma unroll
      for (int r = 0; r < 4; ++r)
        xqkv[(size_t)(m0 + mi * 16 + q * 4 + r) * 768 + col] = __float2bfloat16(acc[mi][ni][r] + b);
  }
}

// ---------------------------------------------------------------- fused per-point transform (sorted-space gathers)
__global__ __launch_bounds__(256) void fused_pt(
    const float4* __restrict__ sp4, const int* __restrict__ sidx, const int* __restrict__ rank,
    const __hip_bfloat16* __restrict__ xqkv, const int* __restrict__ nbr,
    const float* __restrict__ pw1, const float* __restrict__ pb1,
    const float* __restrict__ pbng, const float* __restrict__ pbnb,
    const float* __restrict__ pbnm, const float* __restrict__ pbnv,
    const float* __restrict__ pw2, const float* __restrict__ pb2,
    const float* __restrict__ bn1g, const float* __restrict__ bn1b,
    const float* __restrict__ bn1m, const float* __restrict__ bn1v,
    const __hip_bfloat16* __restrict__ l1wp, const float* __restrict__ l1b,
    const float* __restrict__ bn2g, const float* __restrict__ bn2b,
    const float* __restrict__ bn2m, const float* __restrict__ bn2v,
    const __hip_bfloat16* __restrict__ l2wp, const float* __restrict__ l2b,
    float* __restrict__ out) {
  __shared__ __align__(16) __hip_bfloat16 a_s[NSAMP][264];
  __shared__ __align__(16) __hip_bfloat16 h1_s[NSAMP][40];
  __shared__ float w_s[NSAMP][33];
  __shared__ float q3_s[NSAMP][4];
  __shared__ int jn[NSAMP];

  const int b = blockIdx.x;            // sorted position
  const int i = sidx[b];               // original index
  const int tid = threadIdx.x;

  if (tid < NSAMP) {
    int j = nbr[i * NSAMP + tid];      // orig neighbor id (exact selection)
    int k = rank[j];                   // sorted row
    jn[tid] = k;
    float4 pj = sp4[k];
    float4 pc = sp4[b];
    float rx = pj.x - pc.x;
    float ry = pj.y - pc.y;
    float rz = pj.z - pc.z;
    #pragma unroll
    for (int c3 = 0; c3 < 3; ++c3) {
      float t = rx * pw1[0 * 3 + c3] + ry * pw1[1 * 3 + c3] + rz * pw1[2 * 3 + c3] + pb1[c3];
      t = (t - pbnm[c3]) * rsqrtf(pbnv[c3] + EPSBN) * pbng[c3] + pbnb[c3];
      q3_s[tid][c3] = fmaxf(t, 0.f);
    }
  }
  __syncthreads();

  const int c = tid;
  const float xq_c = __bfloat162float(xqkv[(size_t)b * 768 + c]);
  const float s1 = bn1g[c] * rsqrtf(bn1v[c] + EPSBN);
  const float o1 = bn1b[c] - bn1m[c] * s1;
  const float w2c0 = pw2[c], w2c1 = pw2[256 + c], w2c2 = pw2[512 + c];
  const float pb2c = pb2[c];
  #pragma unroll
  for (int t = 0; t < NSAMP; ++t) {
    int k = jn[t];
    float prv = q3_s[t][0] * w2c0 + q3_s[t][1] * w2c1 + q3_s[t][2] * w2c2 + pb2c;
    float xkv = __bfloat162float(xqkv[(size_t)k * 768 + 256 + c]);
    float r = xkv - xq_c + prv;
    a_s[t][c] = __float2bfloat16(fmaxf(r * s1 + o1, 0.f));
  }
  __syncthreads();

  const int wv_ = tid >> 6;
  const int lane = tid & 63;
  const int nn = lane & 15, q = lane >> 4;
  if (wv_ < 2) {
    f32x4 acc = {0.f, 0.f, 0.f, 0.f};
    #pragma unroll
    for (int k0 = 0; k0 < 256; k0 += 32) {
      bf16x8 a = *(const bf16x8*)&a_s[nn][k0 + q * 8];
      bf16x8 bb = *(const bf16x8*)&l1wp[wv_ * 4096 + (k0 >> 3) * 128 + q * 128 + nn * 8];
      acc = __builtin_amdgcn_mfma_f32_16x16x32_bf16(a, bb, acc, 0, 0, 0);
    }
    int h = wv_ * 16 + nn;
    float s2 = bn2g[h] * rsqrtf(bn2v[h] + EPSBN);
    float o2 = bn2b[h] - bn2m[h] * s2;
    float l1bh = l1b[h];
    #pragma unroll
    for (int r = 0; r < 4; ++r)
      h1_s[q * 4 + r][h] = __float2bfloat16(fmaxf((acc[r] + l1bh) * s2 + o2, 0.f));
  }
  __syncthreads();

  if (wv_ < 2) {
    bf16x8 a = *(const bf16x8*)&h1_s[nn][q * 8];
    bf16x8 bb = *(const bf16x8*)&l2wp[wv_ * 512 + q * 128 + nn * 8];
    f32x4 z = {0.f, 0.f, 0.f, 0.f};
    f32x4 d = __builtin_amdgcn_mfma_f32_16x16x32_bf16(a, bb, z, 0, 0, 0);
    int h = wv_ * 16 + nn;
    float l2bh = l2b[h];
    #pragma unroll
    for (int r = 0; r < 4; ++r) w_s[q * 4 + r][h] = d[r] + l2bh;
  }
  __syncthreads();

  if (tid < H_W) {
    int h = tid;
    float m = -1e30f;
    #pragma unroll
    for (int t = 0; t < NSAMP; ++t) m = fmaxf(m, w_s[t][h]);
    float e[NSAMP];
    float ssum = 0.f;
    #pragma unroll
    for (int t = 0; t < NSAMP; ++t) { e[t] = __expf(w_s[t][h] - m); ssum += e[t]; }
    float inv = 1.f / ssum;
    #pragma unroll
    for (int t = 0; t < NSAMP; ++t) w_s[t][h] = e[t] * inv;
  }
  __syncthreads();

  const int h = c & 31;
  float acc6 = 0.f;
  #pragma unroll
  for (int t = 0; t < NSAMP; ++t) {
    int k = jn[t];
    float xv = __bfloat162float(xqkv[(size_t)k * 768 + 512 + c]);
    float prv = q3_s[t][0] * w2c0 + q3_s[t][1] * w2c1 + q3_s[t][2] * w2c2 + pb2c;
    acc6 += (xv + prv) * w_s[t][h];
  }
  out[(size_t)i * OUT_C + c] = acc6;
}

// ---------------------------------------------------------------- launch
extern "C" void kernel_launch(void* const* d_in, const int* in_sizes, int n_in,
                              void* d_out, int out_size, void* d_ws, size_t ws_size,
                              hipStream_t stream) {
  const float* p    = (const float*)d_in[0];
  const float* x    = (const float*)d_in[1];
  const float* wq   = (const float*)d_in[2];
  const float* bq   = (const float*)d_in[3];
  const float* wk   = (const float*)d_in[4];
  const float* bk   = (const float*)d_in[5];
  const float* wv   = (const float*)d_in[6];
  const float* bv   = (const float*)d_in[7];
  const float* pw1  = (const float*)d_in[8];
  const float* pb1  = (const float*)d_in[9];
  const float* pbng = (const float*)d_in[10];
  const float* pbnb = (const float*)d_in[11];
  const float* pbnm = (const float*)d_in[12];
  const float* pbnv = (const float*)d_in[13];
  const float* pw2  = (const float*)d_in[14];
  const float* pb2  = (const float*)d_in[15];
  const float* bn1g = (const float*)d_in[16];
  const float* bn1b = (const float*)d_in[17];
  const float* bn1m = (const float*)d_in[18];
  const float* bn1v = (const float*)d_in[19];
  const float* l1w  = (const float*)d_in[20];
  const float* l1b  = (const float*)d_in[21];
  const float* bn2g = (const float*)d_in[22];
  const float* bn2b = (const float*)d_in[23];
  const float* bn2m = (const float*)d_in[24];
  const float* bn2v = (const float*)d_in[25];
  const float* l2w  = (const float*)d_in[26];
  const float* l2b  = (const float*)d_in[27];
  float* out = (float*)d_out;

  char* ws = (char*)d_ws;
  float4* p4       = (float4*)(ws + 0x000000);
  float*  biasp    = (float*)(ws + 0x040000);
  int*    hist     = (int*)(ws + 0x042000);
  int*    cursor   = (int*)(ws + 0x042800);
  int*    cell_st  = (int*)(ws + 0x043000);
  int*    pt_cell  = (int*)(ws + 0x044000);
  float4* sp4      = (float4*)(ws + 0x050000);
  int*    sidx     = (int*)(ws + 0x070000);
  __hip_bfloat16* l1wp = (__hip_bfloat16*)(ws + 0x080000);
  __hip_bfloat16* l2wp = (__hip_bfloat16*)(ws + 0x084000);
  int*    rank     = (int*)(ws + 0x088000);
  int*    nbr      = (int*)(ws + 0x090000);
  __hip_bfloat16* Bp   = (__hip_bfloat16*)(ws + 0x110000);
  __hip_bfloat16* x_bf = (__hip_bfloat16*)(ws + 0x170000);
  __hip_bfloat16* xqkv = (__hip_bfloat16*)(ws + 0x570000);

  hipMemsetAsync(ws + 0x042000, 0, 0x1000, stream);  // hist + cursor
  prep_kernel<<<dim3(768), dim3(256), 0, stream>>>(
      p, wq, wk, wv, bq, bk, bv, l1w, l2w, p4, Bp, biasp, l1wp, l2wp,
      hist, pt_cell);
  scan512<<<dim3(1), dim3(NCELL), 0, stream>>>(hist, cell_st);
  scatter_kernel<<<dim3(32), dim3(256), 0, stream>>>(p4, pt_cell, cell_st, cursor, sp4, sidx, rank);
  xbf_kernel<<<dim3(N_PTS), dim3(256), 0, stream>>>(x, sidx, x_bf);
  gemm_qkv_mfma<<<dim3(384), dim3(256), 0, stream>>>(x_bf, Bp, biasp, xqkv);
  knn_grid<<<dim3(NCELL * 2), dim3(256), 0, stream>>>(sp4, sidx, cell_st, nbr);
  fused_pt<<<dim3(N_PTS), dim3(256), 0, stream>>>(
      sp4, sidx, rank, xqkv, nbr, pw1, pb1, pbng, pbnb, pbnm, pbnv, pw2, pb2,
      bn1g, bn1b, bn1m, bn1v, l1wp, l1b, bn2g, bn2b, bn2m, bn2v, l2wp, l2b, out);
}